// Round 6
// baseline (125.395 us; speedup 1.0000x reference)
//
#include <hip/hip_runtime.h>
#include <math.h>

#define BB 524288
#define CC 10
#define TT 25
#define BLK 256
#define NBLK (BB / BLK)          // 2048 blocks
#define SLABF ((size_t)BB * CC)  // eps floats per t-slab

typedef float v2f __attribute__((ext_vector_type(2)));

__global__ __launch_bounds__(256) void mc_nll_kernel(
    const float* __restrict__ mu,
    const float* __restrict__ ls2,
    const int*   __restrict__ y,
    const float* __restrict__ eps,
    float* __restrict__ ws)
{
    const int b = blockIdx.x * BLK + threadIdx.x;

    const int yi = y[b];

    // ---- per-b params (float2, stride-40; ~7% of traffic) ----
    float muv[CC], sig[CC];
    {
        const float2* m2 = reinterpret_cast<const float2*>(mu  + (size_t)b * CC);
        const float2* s2 = reinterpret_cast<const float2*>(ls2 + (size_t)b * CC);
#pragma unroll
        for (int i = 0; i < CC / 2; ++i) {
            float2 m = m2[i];
            float2 s = s2[i];
            muv[2 * i]     = m.x;
            muv[2 * i + 1] = m.y;
            sig[2 * i]     = __expf(0.5f * s.x);
            sig[2 * i + 1] = __expf(0.5f * s.y);
        }
    }

    // ---- direct streaming over the T samples ----
    // logit_y <= logsumexp_c always => per-sample exp(v) = e_y / s in (0,1];
    // direct sum over t (absmax 0.0 in R3/R4), no online max, no per-t log.
    float S = 0.0f;
    for (int t = 0; t < TT; ++t) {
        const v2f* e2 = reinterpret_cast<const v2f*>(
            eps + (size_t)t * SLABF + (size_t)b * CC);
        float l[CC];
#pragma unroll
        for (int i = 0; i < CC / 2; ++i) {
            v2f e = __builtin_nontemporal_load(e2 + i);   // single-use stream
            l[2 * i]     = fmaf(sig[2 * i],     e.x, muv[2 * i]);
            l[2 * i + 1] = fmaf(sig[2 * i + 1], e.y, muv[2 * i + 1]);
        }
        float m = l[0];
#pragma unroll
        for (int c = 1; c < CC; ++c) m = fmaxf(m, l[c]);
        float s = 0.0f, ey = 0.0f;
#pragma unroll
        for (int c = 0; c < CC; ++c) {
            float x = __expf(l[c] - m);
            s += x;
            ey = (c == yi) ? x : ey;
        }
        S = fmaf(ey, __builtin_amdgcn_rcpf(s), S);
    }

    // ---- block reduction: wave shuffle -> LDS -> ONE PLAIN STORE per block ----
    float x = __logf(S);
#pragma unroll
    for (int off = 32; off > 0; off >>= 1)
        x += __shfl_down(x, off, 64);

    __shared__ float wsum[4];
    const int lane = threadIdx.x & 63;
    const int wid  = threadIdx.x >> 6;
    if (lane == 0) wsum[wid] = x;
    __syncthreads();
    if (threadIdx.x == 0)
        ws[blockIdx.x] = wsum[0] + wsum[1] + wsum[2] + wsum[3];
}

// Final reduce: 2048 partials -> scalar. Overwrites out each call (no init needed).
__global__ __launch_bounds__(256) void reduce_kernel(
    const float* __restrict__ ws, float* __restrict__ out)
{
    const int tid = threadIdx.x;
    float x = 0.0f;
#pragma unroll
    for (int j = 0; j < NBLK / 256; ++j)
        x += ws[j * 256 + tid];
#pragma unroll
    for (int off = 32; off > 0; off >>= 1)
        x += __shfl_down(x, off, 64);

    __shared__ float wsum[4];
    const int lane = tid & 63;
    const int wid  = tid >> 6;
    if (lane == 0) wsum[wid] = x;
    __syncthreads();
    if (tid == 0) {
        float total = wsum[0] + wsum[1] + wsum[2] + wsum[3];
        *out = logf((float)TT) - total * (1.0f / (float)BB);
    }
}

extern "C" void kernel_launch(void* const* d_in, const int* in_sizes, int n_in,
                              void* d_out, int out_size, void* d_ws, size_t ws_size,
                              hipStream_t stream) {
    const float* mu  = (const float*)d_in[0];
    const float* ls2 = (const float*)d_in[1];
    const int*   y   = (const int*)d_in[2];
    const float* eps = (const float*)d_in[3];
    float* out = (float*)d_out;
    float* ws  = (float*)d_ws;   // 2048 floats, fully rewritten every call

    hipLaunchKernelGGL(mc_nll_kernel, dim3(NBLK), dim3(BLK), 0, stream,
                       mu, ls2, y, eps, ws);
    hipLaunchKernelGGL(reduce_kernel, dim3(1), dim3(BLK), 0, stream, ws, out);
}

// Round 7
// 100.084 us; speedup vs baseline: 1.2529x; 1.2529x over previous
//
#include <hip/hip_runtime.h>
#include <math.h>

#define BB 524288
#define CC 10
#define TT 25
#define BLK 256
#define NBLK (BB / BLK)          // 2048 blocks
#define SLABF ((size_t)BB * CC)  // eps floats per t-slab

__global__ __launch_bounds__(256) void mc_nll_kernel(
    const float* __restrict__ mu,
    const float* __restrict__ ls2,
    const int*   __restrict__ y,
    const float* __restrict__ eps,
    float* __restrict__ ws)
{
    const int b = blockIdx.x * BLK + threadIdx.x;

    const int yi = y[b];

    // ---- per-b params (float2, stride-40; ~7% of traffic) ----
    float muv[CC], sig[CC];
    {
        const float2* m2 = reinterpret_cast<const float2*>(mu  + (size_t)b * CC);
        const float2* s2 = reinterpret_cast<const float2*>(ls2 + (size_t)b * CC);
#pragma unroll
        for (int i = 0; i < CC / 2; ++i) {
            float2 m = m2[i];
            float2 s = s2[i];
            muv[2 * i]     = m.x;
            muv[2 * i + 1] = m.y;
            sig[2 * i]     = __expf(0.5f * s.x);
            sig[2 * i + 1] = __expf(0.5f * s.y);
        }
    }

    // ---- direct streaming over the T samples (plain cached loads, as in R1) ----
    // logit_y <= logsumexp_c always => per-sample exp(v) = e_y / s in (0,1];
    // direct sum over t (absmax 0.0 in R3/R4/R6), no online max, no per-t log.
    float S = 0.0f;
    for (int t = 0; t < TT; ++t) {
        const float2* e2 = reinterpret_cast<const float2*>(
            eps + (size_t)t * SLABF + (size_t)b * CC);
        float l[CC];
#pragma unroll
        for (int i = 0; i < CC / 2; ++i) {
            float2 e = e2[i];
            l[2 * i]     = fmaf(sig[2 * i],     e.x, muv[2 * i]);
            l[2 * i + 1] = fmaf(sig[2 * i + 1], e.y, muv[2 * i + 1]);
        }
        float m = l[0];
#pragma unroll
        for (int c = 1; c < CC; ++c) m = fmaxf(m, l[c]);
        float s = 0.0f, ey = 0.0f;
#pragma unroll
        for (int c = 0; c < CC; ++c) {
            float x = __expf(l[c] - m);
            s += x;
            ey = (c == yi) ? x : ey;
        }
        S = fmaf(ey, __builtin_amdgcn_rcpf(s), S);
    }

    // ---- block reduction: wave shuffle -> LDS -> ONE PLAIN STORE per block ----
    float x = __logf(S);
#pragma unroll
    for (int off = 32; off > 0; off >>= 1)
        x += __shfl_down(x, off, 64);

    __shared__ float wsum[4];
    const int lane = threadIdx.x & 63;
    const int wid  = threadIdx.x >> 6;
    if (lane == 0) wsum[wid] = x;
    __syncthreads();
    if (threadIdx.x == 0)
        ws[blockIdx.x] = wsum[0] + wsum[1] + wsum[2] + wsum[3];
}

// Final reduce: 2048 partials -> scalar. Overwrites out each call (no init needed).
__global__ __launch_bounds__(256) void reduce_kernel(
    const float* __restrict__ ws, float* __restrict__ out)
{
    const int tid = threadIdx.x;
    float x = 0.0f;
#pragma unroll
    for (int j = 0; j < NBLK / 256; ++j)
        x += ws[j * 256 + tid];
#pragma unroll
    for (int off = 32; off > 0; off >>= 1)
        x += __shfl_down(x, off, 64);

    __shared__ float wsum[4];
    const int lane = tid & 63;
    const int wid  = tid >> 6;
    if (lane == 0) wsum[wid] = x;
    __syncthreads();
    if (tid == 0) {
        float total = wsum[0] + wsum[1] + wsum[2] + wsum[3];
        *out = logf((float)TT) - total * (1.0f / (float)BB);
    }
}

extern "C" void kernel_launch(void* const* d_in, const int* in_sizes, int n_in,
                              void* d_out, int out_size, void* d_ws, size_t ws_size,
                              hipStream_t stream) {
    const float* mu  = (const float*)d_in[0];
    const float* ls2 = (const float*)d_in[1];
    const int*   y   = (const int*)d_in[2];
    const float* eps = (const float*)d_in[3];
    float* out = (float*)d_out;
    float* ws  = (float*)d_ws;   // 2048 floats, fully rewritten every call

    hipLaunchKernelGGL(mc_nll_kernel, dim3(NBLK), dim3(BLK), 0, stream,
                       mu, ls2, y, eps, ws);
    hipLaunchKernelGGL(reduce_kernel, dim3(1), dim3(BLK), 0, stream, ws, out);
}